// Round 1
// baseline (339.035 us; speedup 1.0000x reference)
//
#include <hip/hip_runtime.h>

// Conv2d int32 (values fit int8) via implicit GEMM on i8 MFMA.
// O[b,co,h,w] = sum_{ci,kh,kw} x[b,ci,h+kh-1,w+kw-1]*w[co,ci,kh,kw] + bias[co]
// M = co, N = pixels (row-pair, 64 slots/row), K = ci (chunks of 64) x 9 shifts.
// mfma_i32_16x16x64_i8: A m=lane&15,k=(lane>>4)*16+j ; C/D col=lane&15,row=(lane>>4)*4+reg

typedef int v4i __attribute__((ext_vector_type(4)));

#define THREADS 512

__global__ __launch_bounds__(THREADS, 2)
void conv_i8_mfma(const int* __restrict__ x, const int* __restrict__ wgt,
                  const int* __restrict__ bias, int* __restrict__ out) {
  // LDS: wls [64 co][9 s][80 ci-pad]   = 46080 B (stride 80 -> 20-bank step, 2-way = free)
  //      xs  [4 row][58 idx][80 ci-pad] = 18560 B
  __shared__ __align__(16) unsigned char lds[64640];
  unsigned char* wls = lds;
  unsigned char* xs  = lds + 46080;

  const int tid  = threadIdx.x;
  const int lane = tid & 63;
  const int wv   = tid >> 6;     // 0..7
  const int cw   = wv & 3;       // which 16-co slice
  const int pw   = wv >> 2;      // which output row of the pair
  const int q    = lane >> 4;    // k-group (0..3)
  const int m    = lane & 15;

  const int co0 = blockIdx.x << 6;   // 4 co-tiles of 64
  const int h0  = blockIdx.y << 1;   // 28 row-pairs
  const int b   = blockIdx.z;        // 16 batches

  v4i acc[4];
  #pragma unroll
  for (int i = 0; i < 4; ++i) acc[i] = (v4i){0, 0, 0, 0};

  for (int c0 = 0; c0 < 256; c0 += 64) {
    __syncthreads();
    // ---- stage weights: 64 co x 64 ci x 9 taps, int32 -> int8 ----
    for (int e = tid; e < 64 * 64 * 9; e += THREADS) {
      const int co  = e / 576;
      const int rem = e - co * 576;
      const int ci  = rem / 9;
      const int s   = rem - ci * 9;           // global reads contiguous in (ci,s)
      const int v   = wgt[(co0 + co) * 2304 + (c0 + ci) * 9 + s];
      wls[co * 720 + s * 80 + ci] = (unsigned char)v;
    }
    // ---- stage x: 4 input rows x 58 w-slots (iw = idx-1) x 64 ci, packed 4 ci/dword ----
    for (int e = tid; e < 16 * 4 * 58; e += THREADS) {
      const int idx = e % 58;
      const int t2  = e / 58;
      const int row = t2 & 3;
      const int grp = t2 >> 2;                // 0..15 -> ci = grp*4
      const int iw  = idx - 1;
      const int ih  = h0 + row - 1;
      unsigned int pack = 0u;
      if ((unsigned)iw < 56u && (unsigned)ih < 56u) {
        const int* xp = x + ((b * 256 + c0 + grp * 4) * 56 + ih) * 56 + iw;
        const unsigned int v0 = (unsigned)xp[0];
        const unsigned int v1 = (unsigned)xp[3136];
        const unsigned int v2 = (unsigned)xp[6272];
        const unsigned int v3 = (unsigned)xp[9408];
        pack = (v0 & 255u) | ((v1 & 255u) << 8) | ((v2 & 255u) << 16) | ((v3 & 255u) << 24);
      }
      *(unsigned int*)(xs + row * 4640 + idx * 80 + grp * 4) = pack;
    }
    __syncthreads();
    // ---- compute: 9 shifts x 4 n-tiles, one K=64 MFMA each ----
    const unsigned char* wbase = wls + (cw * 16 + m) * 720 + q * 16;
    #pragma unroll
    for (int kh = 0; kh < 3; ++kh) {
      #pragma unroll
      for (int kw = 0; kw < 3; ++kw) {
        const v4i a = *(const v4i*)(wbase + (kh * 3 + kw) * 80);
        const unsigned char* xb = xs + (pw + kh) * 4640 + q * 16;
        #pragma unroll
        for (int nt = 0; nt < 4; ++nt) {
          int idx = nt * 16 + m + kw;          // = w + kw, clamp dead lanes in-bounds
          idx = idx > 57 ? 57 : idx;
          const v4i bf = *(const v4i*)(xb + idx * 80);
          acc[nt] = __builtin_amdgcn_mfma_i32_16x16x64_i8(a, bf, acc[nt], 0, 0, 0);
        }
      }
    }
  }

  // ---- epilogue: bias + store (int32), cols = pixels -> coalesced in w ----
  const int h = h0 + pw;
  #pragma unroll
  for (int nt = 0; nt < 4; ++nt) {
    const int wp = nt * 16 + m;
    if (wp < 56) {
      #pragma unroll
      for (int r = 0; r < 4; ++r) {
        const int co = co0 + cw * 16 + q * 4 + r;
        out[((b * 256 + co) * 56 + h) * 56 + wp] = acc[nt][r] + bias[co];
      }
    }
  }
}

extern "C" void kernel_launch(void* const* d_in, const int* in_sizes, int n_in,
                              void* d_out, int out_size, void* d_ws, size_t ws_size,
                              hipStream_t stream) {
  const int* x    = (const int*)d_in[0];
  const int* w    = (const int*)d_in[1];
  const int* bias = (const int*)d_in[2];
  int* out        = (int*)d_out;
  dim3 grid(4, 28, 16);
  dim3 block(THREADS);
  hipLaunchKernelGGL(conv_i8_mfma, grid, block, 0, stream, x, w, bias, out);
}

// Round 2
// 146.660 us; speedup vs baseline: 2.3117x; 2.3117x over previous
//
#include <hip/hip_runtime.h>

// Conv2d int32 (values fit int8) via implicit GEMM on i8 MFMA, v2.
// Prepass packs x -> int8 x8[chunk(4)][b(16)][row 0..57][slot 0..57][80B] (halo zeroed, pad bytes 64..79 never read)
//         packs w -> int8 w8[tc(4)][chunk(4)][co64][s(9)][ci64]
// Main kernel stages both via global_load_lds width=16 (contiguous images), MFMA 16x16x64 i8.
// Wave = 32 co x 64 px: 54 ds_read_b128 per 72 MFMAs.

typedef int v4i __attribute__((ext_vector_type(4)));

#define X8_ROWSTRIDE 4640              // 58 slots * 80 B
#define X8_IMGSTRIDE 269120            // 58 rows * 4640
#define X8_BYTES (64 * X8_IMGSTRIDE)   // 4 chunks * 16 batch = 17,223,680 B
#define W8_TILE 36864                  // 64 co * 9 s * 64 ci
#define WLS_BYTES 36864
#define XS_OFF WLS_BYTES               // xs region: 28,672 B (27,840 used + copy overrun pad)
#define LDS_BYTES 65536

typedef const __attribute__((address_space(1))) unsigned char* gptr_t;
typedef __attribute__((address_space(3))) unsigned char* lptr_t;

// ---- prepass: x int32 NCHW -> x8 int8 ----
__global__ __launch_bounds__(256)
void pack_x(const int* __restrict__ x, unsigned char* __restrict__ x8) {
  const int ih = blockIdx.x;   // 0..55
  const int b  = blockIdx.y;   // 0..15
  for (int gid = threadIdx.x; gid < 896; gid += 256) {
    const int slot  = gid % 56;          // = iw
    const int cg    = gid / 56;
    const int chunk = cg >> 2;
    const int gr    = cg & 3;            // 16-byte granule within 64 ci
    const int* xp = x + ((b * 256 + chunk * 64 + gr * 16) * 56 + ih) * 56 + slot;
    union { v4i v; unsigned char c[16]; } u;
    #pragma unroll
    for (int j = 0; j < 16; ++j) u.c[j] = (unsigned char)xp[j * 3136];
    *(v4i*)(x8 + (chunk * 16 + b) * X8_IMGSTRIDE + (ih + 1) * X8_ROWSTRIDE
          + (slot + 1) * 80 + gr * 16) = u.v;
  }
}

// ---- prepass: zero halo rows 0,57 and slots 0,57 of each image ----
__global__ __launch_bounds__(256)
void zero_halo(unsigned char* __restrict__ x8) {
  unsigned char* base = x8 + blockIdx.x * X8_IMGSTRIDE;   // 64 images
  for (int e = threadIdx.x; e < 1140; e += 256) {
    int off;
    if (e < 580) {                       // rows 0 and 57: 290 x 16B each
      const int half = e < 290 ? 0 : 1;
      const int g = e - half * 290;
      off = half * (57 * X8_ROWSTRIDE) + g * 16;
    } else {                             // slots 0 and 57, rows 1..56: 80 B each
      const int f = e - 580;
      const int r = f / 10 + 1;
      const int pos = f - (r - 1) * 10;
      const int side = pos / 5, g = pos - side * 5;
      off = r * X8_ROWSTRIDE + side * (57 * 80) + g * 16;
    }
    *(v4i*)(base + off) = (v4i){0, 0, 0, 0};
  }
}

// ---- prepass: w int32 OIHW -> w8 int8 ----
__global__ __launch_bounds__(256)
void pack_w(const int* __restrict__ wgt, unsigned char* __restrict__ w8) {
  const int id = blockIdx.x * 256 + threadIdx.x;    // 589,824 elems
  const int co = id / 2304;
  const int r  = id - co * 2304;
  const int ci = r / 9;
  const int s  = r - ci * 9;
  const int tc = co >> 6, co64 = co & 63, chunk = ci >> 6, ci64 = ci & 63;
  w8[(((tc * 4 + chunk) * 64 + co64) * 576) + s * 64 + ci64] = (unsigned char)wgt[id];
}

// ---- main: 64 co x 4 rows x 56 w per block; wave = 32 co x 64 px ----
__global__ __launch_bounds__(512, 4)
void conv_main(const unsigned char* __restrict__ ws8, const int* __restrict__ bias,
               int* __restrict__ out) {
  __shared__ __align__(16) unsigned char lds[LDS_BYTES];
  unsigned char* wls = lds;            // [64 co][9 s][64 ci]
  unsigned char* xs  = lds + XS_OFF;   // [6 rows][58 slots][80]
  const unsigned char* x8 = ws8;
  const unsigned char* w8 = ws8 + X8_BYTES;

  const int tid = threadIdx.x, lane = tid & 63, wv = tid >> 6;
  const int q = lane >> 4, m = lane & 15;
  const int cw = wv & 1;               // co half (32)
  const int pw = wv >> 1;              // output row 0..3
  const int tc = blockIdx.x;           // co tile of 64
  const int h0 = blockIdx.y * 4;       // 14 row-quads
  const int b  = blockIdx.z;

  v4i acc[2][4];
  #pragma unroll
  for (int i = 0; i < 2; ++i)
    #pragma unroll
    for (int j = 0; j < 4; ++j) acc[i][j] = (v4i){0, 0, 0, 0};

  for (int c = 0; c < 4; ++c) {
    __syncthreads();
    // weights: 36,864 B contiguous -> wls
    const unsigned char* wg = w8 + (tc * 4 + c) * W8_TILE;
    #pragma unroll
    for (int i = 0; i < 5; ++i) {
      const int j = i * 8 + wv;                       // wave-uniform guard
      if (j < 36)
        __builtin_amdgcn_global_load_lds((gptr_t)(wg + j * 1024 + lane * 16),
                                         (lptr_t)(wls + j * 1024), 16, 0, 0);
    }
    // x: 6 rows = 27,840 B contiguous (padded copy to 28,672; overrun reads land in w8)
    const unsigned char* xg = x8 + (c * 16 + b) * X8_IMGSTRIDE + h0 * X8_ROWSTRIDE;
    #pragma unroll
    for (int i = 0; i < 4; ++i) {
      const int j = i * 8 + wv;
      if (j < 28)
        __builtin_amdgcn_global_load_lds((gptr_t)(xg + j * 1024 + lane * 16),
                                         (lptr_t)(xs + j * 1024), 16, 0, 0);
    }
    __syncthreads();
    // compute: 9 taps x (2 A + 4 B reads, 8 MFMAs)
    const unsigned char* arow = wls + (cw * 32 + m) * 576 + q * 16;
    #pragma unroll
    for (int kh = 0; kh < 3; ++kh) {
      const unsigned char* xr = xs + (pw + kh) * X8_ROWSTRIDE + q * 16;
      #pragma unroll
      for (int kw = 0; kw < 3; ++kw) {
        const int s = kh * 3 + kw;
        const v4i a0 = *(const v4i*)(arow + s * 64);
        const v4i a1 = *(const v4i*)(arow + 16 * 576 + s * 64);
        #pragma unroll
        for (int nt = 0; nt < 4; ++nt) {
          int idx = nt * 16 + m + kw;      // = wp + kw; clamp dead lanes in-bounds
          idx = idx > 57 ? 57 : idx;
          const v4i bf = *(const v4i*)(xr + idx * 80);
          acc[0][nt] = __builtin_amdgcn_mfma_i32_16x16x64_i8(a0, bf, acc[0][nt], 0, 0, 0);
          acc[1][nt] = __builtin_amdgcn_mfma_i32_16x16x64_i8(a1, bf, acc[1][nt], 0, 0, 0);
        }
      }
    }
  }

  // epilogue: bias + coalesced-in-w int32 stores
  const int h = h0 + pw;
  #pragma unroll
  for (int half = 0; half < 2; ++half) {
    #pragma unroll
    for (int nt = 0; nt < 4; ++nt) {
      const int wp = nt * 16 + m;
      if (wp < 56) {
        #pragma unroll
        for (int r = 0; r < 4; ++r) {
          const int co = tc * 64 + cw * 32 + half * 16 + q * 4 + r;
          out[((b * 256 + co) * 56 + h) * 56 + wp] = acc[half][nt][r] + bias[co];
        }
      }
    }
  }
}

extern "C" void kernel_launch(void* const* d_in, const int* in_sizes, int n_in,
                              void* d_out, int out_size, void* d_ws, size_t ws_size,
                              hipStream_t stream) {
  const int* x    = (const int*)d_in[0];
  const int* w    = (const int*)d_in[1];
  const int* bias = (const int*)d_in[2];
  unsigned char* ws8 = (unsigned char*)d_ws;   // x8 at 0, w8 after (needs ~17.9 MB)
  hipLaunchKernelGGL(pack_x,    dim3(56, 16), dim3(256), 0, stream, x, ws8);
  hipLaunchKernelGGL(zero_halo, dim3(64),     dim3(256), 0, stream, ws8);
  hipLaunchKernelGGL(pack_w,    dim3(2304),   dim3(256), 0, stream, w, ws8 + X8_BYTES);
  hipLaunchKernelGGL(conv_main, dim3(4, 14, 16), dim3(512), 0, stream,
                     ws8, bias, (int*)d_out);
}

// Round 3
// 136.218 us; speedup vs baseline: 2.4889x; 1.0767x over previous
//
#include <hip/hip_runtime.h>

// Conv2d int32 (values fit int8) via implicit GEMM on i8 MFMA, v3.
// One fused prepass packs x and w to int8 in LDS-image layout with an XOR
// bank swizzle baked in: within each 64B K-block, K-granule q lives at
// position (q + (idx>>2))&3 (idx = slot for x, co for w). This makes every
// ds_read_b128 in the main kernel 2-way-per-bank (free) and lets the x image
// use 64B slot stride (no pad), since global_load_lds copies it verbatim.

typedef int v4i __attribute__((ext_vector_type(4)));

#define X8_ROWSTRIDE 3712                 // 58 slots * 64 B
#define X8_IMGSTRIDE (58 * X8_ROWSTRIDE)  // 215,296
#define X8_BYTES (64 * X8_IMGSTRIDE)      // 13,778,944
#define W8_TILE 36864                     // 64 co * 9 s * 64 ci
#define XS_OFF 36864
#define LDS_BYTES 59648                   // 36,864 wls + 22,528 xs(+overrun pad)

typedef const __attribute__((address_space(1))) unsigned char* gptr_t;
typedef __attribute__((address_space(3))) unsigned char* lptr_t;

// ---- fused prepass: x int32 NCHW -> x8 (halo zeroed), w int32 OIHW -> w8 ----
__global__ __launch_bounds__(256)
void pack_all(const int* __restrict__ x, const int* __restrict__ wgt,
              unsigned char* __restrict__ ws8) {
  const int blk = blockIdx.x;
  if (blk < 3712) {
    // x part: one (chunk,b,row) per block; 232 threads write 16B granules.
    const int row = blk % 58;
    const int cb  = blk / 58;            // chunk*16 + b
    const int chunk = cb >> 4, b = cb & 15;
    const int tid = threadIdx.x;
    if (tid >= 232) return;
    const int slot = tid >> 2, p = tid & 3;
    union { v4i v; unsigned char c[16]; } u;
    u.v = (v4i){0, 0, 0, 0};
    if (row >= 1 && row <= 56 && slot >= 1 && slot <= 56) {
      const int q = (p - (slot >> 2)) & 3;                 // source K-granule
      const unsigned char* src = (const unsigned char*)(x
          + ((b * 256 + chunk * 64 + q * 16) * 56 + (row - 1)) * 56 + (slot - 1));
      #pragma unroll
      for (int j = 0; j < 16; ++j) u.c[j] = src[j * 12544]; // low byte of int32
    }
    *(v4i*)(ws8 + cb * X8_IMGSTRIDE + row * X8_ROWSTRIDE + slot * 64 + p * 16) = u.v;
  } else {
    // w part: 36,864 granules of 16B
    const int g  = (blk - 3712) * 256 + threadIdx.x;
    const int p  = g & 3;
    const int sp = g >> 2;
    const int s  = sp % 9;
    const int ct = sp / 9;               // (tc*4+chunk)*64 + co64
    const int co64 = ct & 63;
    const int tcch = ct >> 6;
    const int tc = tcch >> 2, chunk = tcch & 3;
    const int q = (p - ((co64 >> 2) & 3)) & 3;
    const unsigned char* src = (const unsigned char*)(wgt
        + (tc * 64 + co64) * 2304 + (chunk * 64 + q * 16) * 9 + s);
    union { v4i v; unsigned char c[16]; } u;
    #pragma unroll
    for (int j = 0; j < 16; ++j) u.c[j] = src[j * 36];
    *(v4i*)(ws8 + X8_BYTES + ct * 576 + s * 64 + p * 16) = u.v;
  }
}

// ---- main: 64 co x 4 rows x 56 w per block; wave = 32 co x 64 px ----
__global__ __launch_bounds__(512, 4)
void conv_main(const unsigned char* __restrict__ ws8, const int* __restrict__ bias,
               int* __restrict__ out) {
  __shared__ __align__(16) unsigned char lds[LDS_BYTES];
  unsigned char* wls = lds;            // [64 co][9 s][64 ci] (swizzled by co)
  unsigned char* xs  = lds + XS_OFF;   // [6 rows][58 slots][64] (swizzled by slot)
  const unsigned char* x8 = ws8;
  const unsigned char* w8 = ws8 + X8_BYTES;

  const int tid = threadIdx.x, lane = tid & 63, wv = tid >> 6;
  const int q = lane >> 4, m = lane & 15;
  const int cw = wv & 1;               // co half (32)
  const int pw = wv >> 1;              // output row 0..3
  const int tc = blockIdx.x;           // co tile of 64
  const int h0 = blockIdx.y * 4;       // 14 row-quads
  const int b  = blockIdx.z;

  // A base: swizzle offset depends only on (q, m) -> fold in once.
  const unsigned char* arow = wls + (cw * 32 + m) * 576 + ((q + (m >> 2)) & 3) * 16;
  // B offsets: slot = nt*16 + m + kw (clamped); swizzle folded per (kw,nt).
  int boff[3][4];
  #pragma unroll
  for (int kw = 0; kw < 3; ++kw)
    #pragma unroll
    for (int nt = 0; nt < 4; ++nt) {
      int slot = nt * 16 + m + kw;
      slot = slot > 57 ? 57 : slot;
      boff[kw][nt] = slot * 64 + ((q + (slot >> 2)) & 3) * 16;
    }

  v4i acc[2][4];
  #pragma unroll
  for (int i = 0; i < 2; ++i)
    #pragma unroll
    for (int j = 0; j < 4; ++j) acc[i][j] = (v4i){0, 0, 0, 0};

  for (int c = 0; c < 4; ++c) {
    __syncthreads();
    // weights: 36,864 B contiguous
    const unsigned char* wg = w8 + (tc * 4 + c) * W8_TILE;
    #pragma unroll
    for (int i = 0; i < 5; ++i) {
      const int j = i * 8 + wv;
      if (j < 36)
        __builtin_amdgcn_global_load_lds((gptr_t)(wg + j * 1024 + lane * 16),
                                         (lptr_t)(wls + j * 1024), 16, 0, 0);
    }
    // x: 6 rows = 22,272 B contiguous (copy rounds up to 22,528; overrun safe)
    const unsigned char* xg = x8 + (c * 16 + b) * X8_IMGSTRIDE + h0 * X8_ROWSTRIDE;
    #pragma unroll
    for (int i = 0; i < 3; ++i) {
      const int j = i * 8 + wv;
      if (j < 22)
        __builtin_amdgcn_global_load_lds((gptr_t)(xg + j * 1024 + lane * 16),
                                         (lptr_t)(xs + j * 1024), 16, 0, 0);
    }
    __syncthreads();
    // compute: 9 taps x (2 A reads + 4 B reads, 8 MFMAs)
    #pragma unroll
    for (int kh = 0; kh < 3; ++kh) {
      const unsigned char* xr = xs + (pw + kh) * X8_ROWSTRIDE;
      #pragma unroll
      for (int kw = 0; kw < 3; ++kw) {
        const int s = kh * 3 + kw;
        const v4i a0 = *(const v4i*)(arow + s * 64);
        const v4i a1 = *(const v4i*)(arow + 16 * 576 + s * 64);
        #pragma unroll
        for (int nt = 0; nt < 4; ++nt) {
          const v4i bf = *(const v4i*)(xr + boff[kw][nt]);
          acc[0][nt] = __builtin_amdgcn_mfma_i32_16x16x64_i8(a0, bf, acc[0][nt], 0, 0, 0);
          acc[1][nt] = __builtin_amdgcn_mfma_i32_16x16x64_i8(a1, bf, acc[1][nt], 0, 0, 0);
        }
      }
    }
  }

  // epilogue: bias + coalesced-in-w int32 stores
  const int h = h0 + pw;
  #pragma unroll
  for (int half = 0; half < 2; ++half) {
    #pragma unroll
    for (int nt = 0; nt < 4; ++nt) {
      const int wp = nt * 16 + m;
      if (wp < 56) {
        #pragma unroll
        for (int r = 0; r < 4; ++r) {
          const int co = tc * 64 + cw * 32 + half * 16 + q * 4 + r;
          out[((b * 256 + co) * 56 + h) * 56 + wp] = acc[half][nt][r] + bias[co];
        }
      }
    }
  }
}

extern "C" void kernel_launch(void* const* d_in, const int* in_sizes, int n_in,
                              void* d_out, int out_size, void* d_ws, size_t ws_size,
                              hipStream_t stream) {
  const int* x    = (const int*)d_in[0];
  const int* w    = (const int*)d_in[1];
  const int* bias = (const int*)d_in[2];
  unsigned char* ws8 = (unsigned char*)d_ws;   // x8 at 0, w8 after (~14.4 MB)
  hipLaunchKernelGGL(pack_all, dim3(3712 + 144), dim3(256), 0, stream, x, w, ws8);
  hipLaunchKernelGGL(conv_main, dim3(4, 14, 16), dim3(512), 0, stream,
                     ws8, bias, (int*)d_out);
}

// Round 4
// 135.896 us; speedup vs baseline: 2.4948x; 1.0024x over previous
//
#include <hip/hip_runtime.h>

// Conv2d int32 (values fit int8) via implicit GEMM, v4: 32x32x32 i8 MFMA.
// x8: [chunk8][b16][row58][slot58][32B]  (halo zeroed, granule parity swizzle (g+slot)&1)
// w8: [cotile4][chunk8][co64][tap9][32B] (granule parity swizzle (g+co)&1)
// Main: block=128thr(2 waves), tile 64co x 4 rows x 56w. Wave = 64co x 128px
// (2 rows x 64 slots, 8 dead w). Per K=32 chunk per tap: 2 A + 4 B ds_read_b128
// feed 8 MFMAs (0.375 reads per 32k ops, half of v3).
// Layouts: A m=lane&31,k=(lane>>5)*16+j ; C/D col=lane&31,row=(r&3)+8*(r>>2)+4*(lane>>5)

typedef int v4i  __attribute__((ext_vector_type(4)));
typedef int v16i __attribute__((ext_vector_type(16)));

#define X8_ROWSTRIDE 1856                 // 58 slots * 32 B
#define X8_IMGSTRIDE 107648               // 58 rows * 1856
#define X8_BYTES     13778944             // 128 images (8 chunks x 16 b)
#define W8_CHUNK     18432                // 64 co * 9 tap * 32 B

typedef const __attribute__((address_space(1))) unsigned char* gptr_t;
typedef __attribute__((address_space(3))) unsigned char* lptr_t;

__device__ __forceinline__ int pack4(const int* p, int stride) {
  return (p[0] & 255) | ((p[stride] & 255) << 8) |
         ((p[2 * stride] & 255) << 16) | ((p[3 * stride] & 255) << 24);
}

// ---- fused prepass: one 16B output granule per thread ----
__global__ __launch_bounds__(256)
void pack_all(const int* __restrict__ x, const int* __restrict__ wgt,
              unsigned char* __restrict__ ws8) {
  const int g = blockIdx.x * 256 + threadIdx.x;
  if (g < 861184) {                       // x part: 8*16*58*58*2 granules
    const int p = g & 1;
    int t = g >> 1;
    const int slot = t % 58; t /= 58;
    const int row  = t % 58;
    const int cb   = t / 58;              // chunk*16 + b
    v4i v = (v4i){0, 0, 0, 0};
    if (row >= 1 && row <= 56 && slot >= 1 && slot <= 56) {
      const int chunk = cb >> 4, b = cb & 15;
      const int srcg = (p + slot) & 1;
      const int ci0 = chunk * 32 + srcg * 16;
      const int* src = x + (b * 256 + ci0) * 3136 + (row - 1) * 56 + (slot - 1);
      v = (v4i){pack4(src, 3136), pack4(src + 4 * 3136, 3136),
                pack4(src + 8 * 3136, 3136), pack4(src + 12 * 3136, 3136)};
    }
    *(v4i*)(ws8 + (cb * 58 + row) * X8_ROWSTRIDE + slot * 32 + p * 16) = v;
  } else {                                // w part: 4*8*64*9*2 granules
    const int gw = g - 861184;
    const int p = gw & 1;
    int t = gw >> 1;
    const int tap = t % 9;  t /= 9;       // t = (cotile*8+chunk)*64 + co
    const int co = t & 63;
    const int tcc = t >> 6;
    const int chunk = tcc & 7, cotile = tcc >> 3;
    const int srcg = (p + co) & 1;
    const int ci0 = chunk * 32 + srcg * 16;
    const int* src = wgt + ((cotile * 64 + co) * 256 + ci0) * 9 + tap;
    v4i v = (v4i){pack4(src, 9), pack4(src + 36, 9),
                  pack4(src + 72, 9), pack4(src + 108, 9)};
    *(v4i*)(ws8 + X8_BYTES + (t * 9 + tap) * 32 + p * 16) = v;
  }
}

// ---- main kernel ----
__global__ __launch_bounds__(128, 2)
void conv_main(const unsigned char* __restrict__ ws8, const int* __restrict__ bias,
               int* __restrict__ out) {
  __shared__ __align__(16) unsigned char lds[18432 + 12288];  // wls + xs(6 rows, +overrun pad)
  __shared__ int bls[64];
  unsigned char* wls = lds;
  unsigned char* xs  = lds + 18432;

  const int tid = threadIdx.x, lane = tid & 63, wv = tid >> 6;  // wv 0..1
  const int n = lane & 31, gq = lane >> 5;
  const int tc = blockIdx.x;             // co tile of 64
  const int h0 = blockIdx.y * 4;         // 14 row-quads
  const int b  = blockIdx.z;

  if (tid < 64) bls[tid] = bias[tc * 64 + tid];

  // A frag offset (co = ct*32 + n; parity swizzle depends on n only)
  const int abase = n * 288 + (((gq + n) & 1) << 4);
  // B frag offsets per (kw, bt): slot = bt*16 + (n&15) + kw, dead lanes clamped
  int boff[3][4];
  #pragma unroll
  for (int kw = 0; kw < 3; ++kw)
    #pragma unroll
    for (int bt = 0; bt < 4; ++bt) {
      int slot = bt * 16 + (n & 15) + kw;
      if (slot > 57) slot = 57;
      boff[kw][bt] = slot * 32 + (((gq + slot) & 1) << 4);
    }
  const int rbase = (2 * wv + (n >> 4)) * X8_ROWSTRIDE;

  v16i acc[2][4];
  #pragma unroll
  for (int i = 0; i < 2; ++i)
    #pragma unroll
    for (int j = 0; j < 4; ++j)
      acc[i][j] = (v16i){0,0,0,0,0,0,0,0,0,0,0,0,0,0,0,0};

  const unsigned char* wg = ws8 + X8_BYTES + tc * (8 * W8_CHUNK);
  const unsigned char* xg = ws8 + b * X8_IMGSTRIDE + h0 * X8_ROWSTRIDE;

  for (int c = 0; c < 8; ++c) {
    __syncthreads();
    // stage weights: 18,432 B = 9 x (128 lanes x 16 B)
    const gptr_t wsrc = (gptr_t)(wg + c * W8_CHUNK);
    #pragma unroll
    for (int i = 0; i < 9; ++i)
      __builtin_amdgcn_global_load_lds(wsrc + i * 2048 + tid * 16,
                                       (lptr_t)(wls + i * 2048 + tid * 16), 16, 0, 0);
    // stage x: 6 rows = 11,136 B, round up to 12,288 (overrun lands in-bounds)
    const gptr_t xsrc = (gptr_t)(xg + c * (16 * X8_IMGSTRIDE));
    #pragma unroll
    for (int i = 0; i < 6; ++i)
      __builtin_amdgcn_global_load_lds(xsrc + i * 2048 + tid * 16,
                                       (lptr_t)(xs + i * 2048 + tid * 16), 16, 0, 0);
    __syncthreads();
    // compute: 9 taps x (2 A reads + 4 B reads, 8 MFMAs)
    #pragma unroll
    for (int kh = 0; kh < 3; ++kh) {
      const unsigned char* xr = xs + rbase + kh * X8_ROWSTRIDE;
      #pragma unroll
      for (int kw = 0; kw < 3; ++kw) {
        const int tap = kh * 3 + kw;
        const v4i a0 = *(const v4i*)(wls + abase + tap * 32);
        const v4i a1 = *(const v4i*)(wls + 9216 + abase + tap * 32);
        #pragma unroll
        for (int bt = 0; bt < 4; ++bt) {
          const v4i bb = *(const v4i*)(xr + boff[kw][bt]);
          acc[0][bt] = __builtin_amdgcn_mfma_i32_32x32x32_i8(a0, bb, acc[0][bt], 0, 0, 0);
          acc[1][bt] = __builtin_amdgcn_mfma_i32_32x32x32_i8(a1, bb, acc[1][bt], 0, 0, 0);
        }
      }
    }
  }

  // epilogue: bias + stores (16 consecutive w per 16-lane group = 64 B segments)
  const int h = h0 + 2 * wv + (n >> 4);
  const int wbase = lane & 15;
  #pragma unroll
  for (int ct = 0; ct < 2; ++ct) {
    #pragma unroll
    for (int r = 0; r < 16; ++r) {
      const int co64 = ct * 32 + (r & 3) + 8 * (r >> 2) + 4 * gq;
      const int bv = bls[co64];
      int* orow = out + ((b * 256 + tc * 64 + co64) * 56 + h) * 56;
      #pragma unroll
      for (int bt = 0; bt < 4; ++bt) {
        const int w0 = bt * 16 + wbase;
        if (w0 < 56) orow[w0] = acc[ct][bt][r] + bv;
      }
    }
  }
}

extern "C" void kernel_launch(void* const* d_in, const int* in_sizes, int n_in,
                              void* d_out, int out_size, void* d_ws, size_t ws_size,
                              hipStream_t stream) {
  const int* x    = (const int*)d_in[0];
  const int* w    = (const int*)d_in[1];
  const int* bias = (const int*)d_in[2];
  unsigned char* ws8 = (unsigned char*)d_ws;   // x8 then w8 (~14.4 MB)
  hipLaunchKernelGGL(pack_all, dim3(3508), dim3(256), 0, stream, x, w, ws8);
  hipLaunchKernelGGL(conv_main, dim3(4, 14, 16), dim3(128), 0, stream,
                     ws8, bias, (int*)d_out);
}

// Round 5
// 131.471 us; speedup vs baseline: 2.5788x; 1.0337x over previous
//
#include <hip/hip_runtime.h>

// Conv2d int32 (values fit int8) via implicit GEMM, v5: 32x32x32 i8 MFMA.
// x8: [chunk8][b16][row58][slot58][32B] (halo zeroed, granule parity swizzle (g+slot)&1)
// w8: [cotile4][chunk8][co64][tap9][32B] (granule parity swizzle (g+co)&1)
// Main v5: 256 blocks (1/CU), 512 thr (8 waves). Block = 64co x 14 rows x 56w.
// Waves 0-6 compute 2 rows each; wave 7 stages-only. LDS double-buffered;
// chunk c+1 prefetched via global_load_lds while chunk c computes.
// Grid (64,4): cotile = dim y (stride 64 => same XCD for the 4 blocks sharing x).

typedef int v4i  __attribute__((ext_vector_type(4)));
typedef int v16i __attribute__((ext_vector_type(16)));

#define X8_ROWSTRIDE 1856                 // 58 slots * 32 B
#define X8_IMGSTRIDE 107648               // 58 rows * 1856
#define X8_BYTES     13778944             // 128 images (8 chunks x 16 b)
#define W8_CHUNK     18432                // 64 co * 9 tap * 32 B
#define XS_OFF       36864                // after 2 w-buffers
#define XS_BUF       30720                // 16 rows = 29,696 staged, rounded to 3.75*8192

typedef const __attribute__((address_space(1))) unsigned char* gptr_t;
typedef __attribute__((address_space(3))) unsigned char* lptr_t;

__device__ __forceinline__ int pack4(const int* p, int stride) {
  return (p[0] & 255) | ((p[stride] & 255) << 8) |
         ((p[2 * stride] & 255) << 16) | ((p[3 * stride] & 255) << 24);
}

// ---- fused prepass: one 16B output granule per thread (unchanged from v4) ----
__global__ __launch_bounds__(256)
void pack_all(const int* __restrict__ x, const int* __restrict__ wgt,
              unsigned char* __restrict__ ws8) {
  const int g = blockIdx.x * 256 + threadIdx.x;
  if (g < 861184) {                       // x part: 8*16*58*58*2 granules
    const int p = g & 1;
    int t = g >> 1;
    const int slot = t % 58; t /= 58;
    const int row  = t % 58;
    const int cb   = t / 58;              // chunk*16 + b
    v4i v = (v4i){0, 0, 0, 0};
    if (row >= 1 && row <= 56 && slot >= 1 && slot <= 56) {
      const int chunk = cb >> 4, b = cb & 15;
      const int srcg = (p + slot) & 1;
      const int ci0 = chunk * 32 + srcg * 16;
      const int* src = x + (b * 256 + ci0) * 3136 + (row - 1) * 56 + (slot - 1);
      v = (v4i){pack4(src, 3136), pack4(src + 4 * 3136, 3136),
                pack4(src + 8 * 3136, 3136), pack4(src + 12 * 3136, 3136)};
    }
    *(v4i*)(ws8 + (cb * 58 + row) * X8_ROWSTRIDE + slot * 32 + p * 16) = v;
  } else {                                // w part: 4*8*64*9*2 granules
    const int gw = g - 861184;
    const int p = gw & 1;
    int t = gw >> 1;
    const int tap = t % 9;  t /= 9;       // t = (cotile*8+chunk)*64 + co
    const int co = t & 63;
    const int tcc = t >> 6;
    const int chunk = tcc & 7, cotile = tcc >> 3;
    const int srcg = (p + co) & 1;
    const int ci0 = chunk * 32 + srcg * 16;
    const int* src = wgt + ((cotile * 64 + co) * 256 + ci0) * 9 + tap;
    v4i v = (v4i){pack4(src, 9), pack4(src + 36, 9),
                  pack4(src + 72, 9), pack4(src + 108, 9)};
    *(v4i*)(ws8 + X8_BYTES + (t * 9 + tap) * 32 + p * 16) = v;
  }
}

// ---- stage one chunk (w 18,432 B + x 30,720 B) into buffer (c&1) ----
__device__ __forceinline__ void stage_chunk(const unsigned char* wg,
                                            const unsigned char* xg,
                                            unsigned char* ldsb, int c, int tid) {
  const unsigned char* wsrc = wg + c * W8_CHUNK;
  unsigned char* wdst = ldsb + (c & 1) * W8_CHUNK;
  __builtin_amdgcn_global_load_lds((gptr_t)(wsrc + tid * 16),
                                   (lptr_t)(wdst + tid * 16), 16, 0, 0);
  __builtin_amdgcn_global_load_lds((gptr_t)(wsrc + 8192 + tid * 16),
                                   (lptr_t)(wdst + 8192 + tid * 16), 16, 0, 0);
  if (tid < 128)                                        // wave-uniform (waves 0-1)
    __builtin_amdgcn_global_load_lds((gptr_t)(wsrc + 16384 + tid * 16),
                                     (lptr_t)(wdst + 16384 + tid * 16), 16, 0, 0);
  const unsigned char* xsrc = xg + c * (16 * X8_IMGSTRIDE);
  unsigned char* xdst = ldsb + XS_OFF + (c & 1) * XS_BUF;
  #pragma unroll
  for (int i = 0; i < 3; ++i)
    __builtin_amdgcn_global_load_lds((gptr_t)(xsrc + i * 8192 + tid * 16),
                                     (lptr_t)(xdst + i * 8192 + tid * 16), 16, 0, 0);
  if (tid < 384)                                        // wave-uniform (waves 0-5)
    __builtin_amdgcn_global_load_lds((gptr_t)(xsrc + 24576 + tid * 16),
                                     (lptr_t)(xdst + 24576 + tid * 16), 16, 0, 0);
}

// ---- main kernel ----
__global__ __launch_bounds__(512, 2)
void conv_main(const unsigned char* __restrict__ ws8, const int* __restrict__ bias,
               int* __restrict__ out) {
  __shared__ __align__(16) unsigned char lds[2 * W8_CHUNK + 2 * XS_BUF];  // 98,304 B
  __shared__ int bls[64];

  const int tid = threadIdx.x, lane = tid & 63, wv = tid >> 6;  // wv 0..7
  const int n = lane & 31, gq = lane >> 5;
  const int tc = blockIdx.y;             // co tile of 64 (stride-64 ids => same XCD group)
  const int hb = blockIdx.x;             // hg*16 + b
  const int hg = hb >> 4, b = hb & 15;
  const int h0 = hg * 14;

  if (tid < 64) bls[tid] = bias[tc * 64 + tid];

  // A frag offset (co = half*32 + n; parity swizzle depends on n only)
  const int abase = n * 288 + (((gq + n) & 1) << 4);
  // B frag offsets per (kw, bt): slot = bt*16 + (n&15) + kw, dead lanes clamped
  int boff[3][4];
  #pragma unroll
  for (int kw = 0; kw < 3; ++kw)
    #pragma unroll
    for (int bt = 0; bt < 4; ++bt) {
      int slot = bt * 16 + (n & 15) + kw;
      if (slot > 57) slot = 57;
      boff[kw][bt] = slot * 32 + (((gq + slot) & 1) << 4);
    }
  const int rbase = (2 * wv + (n >> 4)) * X8_ROWSTRIDE;   // valid for wv<7

  v16i acc[2][4];
  #pragma unroll
  for (int i = 0; i < 2; ++i)
    #pragma unroll
    for (int j = 0; j < 4; ++j)
      acc[i][j] = (v16i){0,0,0,0,0,0,0,0,0,0,0,0,0,0,0,0};

  const unsigned char* wg = ws8 + X8_BYTES + tc * (8 * W8_CHUNK);
  const unsigned char* xg = ws8 + b * X8_IMGSTRIDE + h0 * X8_ROWSTRIDE;

  stage_chunk(wg, xg, lds, 0, tid);
  for (int c = 0; c < 8; ++c) {
    __syncthreads();                      // drains this wave's loads(c); all waves synced
    if (c < 7) stage_chunk(wg, xg, lds, c + 1, tid);   // prefetch into other buffer
    if (wv < 7) {
      const unsigned char* wls = lds + (c & 1) * W8_CHUNK;
      const unsigned char* xs  = lds + XS_OFF + (c & 1) * XS_BUF;
      #pragma unroll
      for (int kh = 0; kh < 3; ++kh) {
        const unsigned char* xr = xs + rbase + kh * X8_ROWSTRIDE;
        #pragma unroll
        for (int kw = 0; kw < 3; ++kw) {
          const int tap = kh * 3 + kw;
          const v4i a0 = *(const v4i*)(wls + abase + tap * 32);
          const v4i a1 = *(const v4i*)(wls + 9216 + abase + tap * 32);
          #pragma unroll
          for (int bt = 0; bt < 4; ++bt) {
            const v4i bb = *(const v4i*)(xr + boff[kw][bt]);
            acc[0][bt] = __builtin_amdgcn_mfma_i32_32x32x32_i8(a0, bb, acc[0][bt], 0, 0, 0);
            acc[1][bt] = __builtin_amdgcn_mfma_i32_32x32x32_i8(a1, bb, acc[1][bt], 0, 0, 0);
          }
        }
      }
    }
  }

  if (wv >= 7) return;
  // epilogue: bias + stores (16 consecutive w per 16-lane group = 64 B segments)
  const int h = h0 + 2 * wv + (n >> 4);   // <= 55 always
  const int wbase = lane & 15;
  #pragma unroll
  for (int ct = 0; ct < 2; ++ct) {
    #pragma unroll
    for (int r = 0; r < 16; ++r) {
      const int co64 = ct * 32 + (r & 3) + 8 * (r >> 2) + 4 * gq;
      const int bv = bls[co64];
      int* orow = out + ((b * 256 + tc * 64 + co64) * 56 + h) * 56;
      #pragma unroll
      for (int bt = 0; bt < 4; ++bt) {
        const int w0 = bt * 16 + wbase;
        if (w0 < 56) orow[w0] = acc[ct][bt][r] + bv;
      }
    }
  }
}

extern "C" void kernel_launch(void* const* d_in, const int* in_sizes, int n_in,
                              void* d_out, int out_size, void* d_ws, size_t ws_size,
                              hipStream_t stream) {
  const int* x    = (const int*)d_in[0];
  const int* w    = (const int*)d_in[1];
  const int* bias = (const int*)d_in[2];
  unsigned char* ws8 = (unsigned char*)d_ws;   // x8 then w8 (~14.4 MB)
  hipLaunchKernelGGL(pack_all, dim3(3508), dim3(256), 0, stream, x, w, ws8);
  hipLaunchKernelGGL(conv_main, dim3(64, 4, 1), dim3(512), 0, stream,
                     ws8, bias, (int*)d_out);
}

// Round 7
// 130.977 us; speedup vs baseline: 2.5885x; 1.0038x over previous
//
#include <hip/hip_runtime.h>

// Conv2d int32 (values fit int8) via implicit GEMM, v7: 32x32x32 i8 MFMA.
// x8: [chunk8][b16][row58][slot58][32B] (halo zeroed, granule parity swizzle (g+slot)&1)
// w8: [cotile4][chunk8][co64][tap9][32B] (granule parity swizzle (g+co)&1)
// v7 = v6 with the grid-size bug fixed: w-part needs 144 blocks (36,864
// granules), not 288 — v6's extra blocks read wgt out of bounds (core dump).
// pack_all uses 16B/lane dwordx4 loads; conv_main identical to v5.

typedef int v4i  __attribute__((ext_vector_type(4)));
typedef int v16i __attribute__((ext_vector_type(16)));

#define X8_ROWSTRIDE 1856                 // 58 slots * 32 B
#define X8_IMGSTRIDE 107648               // 58 rows * 1856
#define X8_BYTES     13778944             // 128 images (8 chunks x 16 b)
#define W8_CHUNK     18432                // 64 co * 9 tap * 32 B
#define XS_OFF       36864                // after 2 w-buffers
#define XS_BUF       30720                // 16 rows = 29,696 staged, rounded up

typedef const __attribute__((address_space(1))) unsigned char* gptr_t;
typedef __attribute__((address_space(3))) unsigned char* lptr_t;

__device__ __forceinline__ int pack4(const int* p, int stride) {
  return (p[0] & 255) | ((p[stride] & 255) << 8) |
         ((p[2 * stride] & 255) << 16) | ((p[3 * stride] & 255) << 24);
}

// ---- fused prepass ----
// blocks [0,784): x interior. 200,704 threads: (cb128, row 1..56, sq 0..13, srcg 0..1)
//   each loads 16 dwordx4 (16 ch x 4 consecutive iw) and stores 4 granules.
// blocks [784,1012): halo zero stores (58,368 granules = 228 blocks exact).
// blocks [1012,1156): w pack (36,864 granules = 144 blocks exact).
__global__ __launch_bounds__(256)
void pack_all(const int* __restrict__ x, const int* __restrict__ wgt,
              unsigned char* __restrict__ ws8) {
  const int blk = blockIdx.x;
  if (blk < 784) {
    const int gid = blk * 256 + threadIdx.x;
    const int srcg = gid & 1;
    int t = gid >> 1;
    const int sq = t % 14;  t /= 14;      // slots 4sq+1 .. 4sq+4, iw 4sq .. 4sq+3
    const int row = t % 56 + 1;           // 1..56
    const int cb  = t / 56;               // chunk*16 + b
    const int chunk = cb >> 4, b = cb & 15;
    const int ci0 = chunk * 32 + srcg * 16;
    const int* src = x + (b * 256 + ci0) * 3136 + (row - 1) * 56 + 4 * sq;
    v4i L[16];
    #pragma unroll
    for (int ch = 0; ch < 16; ++ch) L[ch] = *(const v4i*)(src + ch * 3136);
    unsigned char* dstrow = ws8 + cb * X8_IMGSTRIDE + row * X8_ROWSTRIDE;
    #pragma unroll
    for (int j = 0; j < 4; ++j) {
      const int slot = 4 * sq + 1 + j;
      v4i g;
      #pragma unroll
      for (int d = 0; d < 4; ++d)
        g[d] = (L[4 * d][j] & 255) | ((L[4 * d + 1][j] & 255) << 8) |
               ((L[4 * d + 2][j] & 255) << 16) | ((L[4 * d + 3][j] & 255) << 24);
      const int p = (srcg + slot) & 1;    // inverse of srcg=(p+slot)&1
      *(v4i*)(dstrow + slot * 32 + p * 16) = g;
    }
  } else if (blk < 1012) {
    const int g2 = (blk - 784) * 256 + threadIdx.x;   // 58,368 granules
    const int cb = g2 / 456;
    const int r  = g2 - cb * 456;
    int off;
    if (r < 232) {                       // rows 0 and 57, all 58 slots x 2 granules
      const int row = r < 116 ? 0 : 57;
      const int rr = r % 116;
      off = row * X8_ROWSTRIDE + (rr >> 1) * 32 + (rr & 1) * 16;
    } else {                             // rows 1..56, slots 0 and 57
      const int r2 = r - 232;            // 0..223
      const int row = (r2 >> 2) + 1;
      const int slot = (r2 & 2) ? 57 : 0;
      off = row * X8_ROWSTRIDE + slot * 32 + (r2 & 1) * 16;
    }
    *(v4i*)(ws8 + cb * X8_IMGSTRIDE + off) = (v4i){0, 0, 0, 0};
  } else {
    const int gw = (blk - 1012) * 256 + threadIdx.x;  // 36,864 granules exact
    const int p = gw & 1;
    int t = gw >> 1;
    const int tap = t % 9;  t /= 9;      // t = (cotile*4... (cotile*8+chunk)*64 + co
    const int co = t & 63;
    const int tcc = t >> 6;              // 0..287: chunk 0..7, cotile 0..3
    const int chunk = tcc & 7, cotile = tcc >> 3;
    const int srcg = (p + co) & 1;
    const int ci0 = chunk * 32 + srcg * 16;
    const int* src = wgt + ((cotile * 64 + co) * 256 + ci0) * 9 + tap;
    v4i v = (v4i){pack4(src, 9), pack4(src + 36, 9),
                  pack4(src + 72, 9), pack4(src + 108, 9)};
    *(v4i*)(ws8 + X8_BYTES + (t * 9 + tap) * 32 + p * 16) = v;
  }
}

// ---- stage one chunk (w 18,432 B + x 30,720 B) into buffer (c&1) ----
__device__ __forceinline__ void stage_chunk(const unsigned char* wg,
                                            const unsigned char* xg,
                                            unsigned char* ldsb, int c, int tid) {
  const unsigned char* wsrc = wg + c * W8_CHUNK;
  unsigned char* wdst = ldsb + (c & 1) * W8_CHUNK;
  __builtin_amdgcn_global_load_lds((gptr_t)(wsrc + tid * 16),
                                   (lptr_t)(wdst + tid * 16), 16, 0, 0);
  __builtin_amdgcn_global_load_lds((gptr_t)(wsrc + 8192 + tid * 16),
                                   (lptr_t)(wdst + 8192 + tid * 16), 16, 0, 0);
  if (tid < 128)                                        // wave-uniform (waves 0-1)
    __builtin_amdgcn_global_load_lds((gptr_t)(wsrc + 16384 + tid * 16),
                                     (lptr_t)(wdst + 16384 + tid * 16), 16, 0, 0);
  const unsigned char* xsrc = xg + c * (16 * X8_IMGSTRIDE);
  unsigned char* xdst = ldsb + XS_OFF + (c & 1) * XS_BUF;
  #pragma unroll
  for (int i = 0; i < 3; ++i)
    __builtin_amdgcn_global_load_lds((gptr_t)(xsrc + i * 8192 + tid * 16),
                                     (lptr_t)(xdst + i * 8192 + tid * 16), 16, 0, 0);
  if (tid < 384)                                        // wave-uniform (waves 0-5)
    __builtin_amdgcn_global_load_lds((gptr_t)(xsrc + 24576 + tid * 16),
                                     (lptr_t)(xdst + 24576 + tid * 16), 16, 0, 0);
}

// ---- main kernel (identical to v5) ----
__global__ __launch_bounds__(512, 2)
void conv_main(const unsigned char* __restrict__ ws8, const int* __restrict__ bias,
               int* __restrict__ out) {
  __shared__ __align__(16) unsigned char lds[2 * W8_CHUNK + 2 * XS_BUF];  // 98,304 B
  __shared__ int bls[64];

  const int tid = threadIdx.x, lane = tid & 63, wv = tid >> 6;  // wv 0..7
  const int n = lane & 31, gq = lane >> 5;
  const int tc = blockIdx.y;             // co tile of 64
  const int hb = blockIdx.x;             // hg*16 + b
  const int hg = hb >> 4, b = hb & 15;
  const int h0 = hg * 14;

  if (tid < 64) bls[tid] = bias[tc * 64 + tid];

  const int abase = n * 288 + (((gq + n) & 1) << 4);
  int boff[3][4];
  #pragma unroll
  for (int kw = 0; kw < 3; ++kw)
    #pragma unroll
    for (int bt = 0; bt < 4; ++bt) {
      int slot = bt * 16 + (n & 15) + kw;
      if (slot > 57) slot = 57;
      boff[kw][bt] = slot * 32 + (((gq + slot) & 1) << 4);
    }
  const int rbase = (2 * wv + (n >> 4)) * X8_ROWSTRIDE;   // valid for wv<7

  v16i acc[2][4];
  #pragma unroll
  for (int i = 0; i < 2; ++i)
    #pragma unroll
    for (int j = 0; j < 4; ++j)
      acc[i][j] = (v16i){0,0,0,0,0,0,0,0,0,0,0,0,0,0,0,0};

  const unsigned char* wg = ws8 + X8_BYTES + tc * (8 * W8_CHUNK);
  const unsigned char* xg = ws8 + b * X8_IMGSTRIDE + h0 * X8_ROWSTRIDE;

  stage_chunk(wg, xg, lds, 0, tid);
  for (int c = 0; c < 8; ++c) {
    __syncthreads();
    if (c < 7) stage_chunk(wg, xg, lds, c + 1, tid);
    if (wv < 7) {
      const unsigned char* wls = lds + (c & 1) * W8_CHUNK;
      const unsigned char* xs  = lds + XS_OFF + (c & 1) * XS_BUF;
      #pragma unroll
      for (int kh = 0; kh < 3; ++kh) {
        const unsigned char* xr = xs + rbase + kh * X8_ROWSTRIDE;
        #pragma unroll
        for (int kw = 0; kw < 3; ++kw) {
          const int tap = kh * 3 + kw;
          const v4i a0 = *(const v4i*)(wls + abase + tap * 32);
          const v4i a1 = *(const v4i*)(wls + 9216 + abase + tap * 32);
          #pragma unroll
          for (int bt = 0; bt < 4; ++bt) {
            const v4i bb = *(const v4i*)(xr + boff[kw][bt]);
            acc[0][bt] = __builtin_amdgcn_mfma_i32_32x32x32_i8(a0, bb, acc[0][bt], 0, 0, 0);
            acc[1][bt] = __builtin_amdgcn_mfma_i32_32x32x32_i8(a1, bb, acc[1][bt], 0, 0, 0);
          }
        }
      }
    }
  }

  if (wv >= 7) return;
  const int h = h0 + 2 * wv + (n >> 4);   // <= 55 always
  const int wbase = lane & 15;
  #pragma unroll
  for (int ct = 0; ct < 2; ++ct) {
    #pragma unroll
    for (int r = 0; r < 16; ++r) {
      const int co64 = ct * 32 + (r & 3) + 8 * (r >> 2) + 4 * gq;
      const int bv = bls[co64];
      int* orow = out + ((b * 256 + tc * 64 + co64) * 56 + h) * 56;
      #pragma unroll
      for (int bt = 0; bt < 4; ++bt) {
        const int w0 = bt * 16 + wbase;
        if (w0 < 56) orow[w0] = acc[ct][bt][r] + bv;
      }
    }
  }
}

extern "C" void kernel_launch(void* const* d_in, const int* in_sizes, int n_in,
                              void* d_out, int out_size, void* d_ws, size_t ws_size,
                              hipStream_t stream) {
  const int* x    = (const int*)d_in[0];
  const int* w    = (const int*)d_in[1];
  const int* bias = (const int*)d_in[2];
  unsigned char* ws8 = (unsigned char*)d_ws;   // x8 then w8 (~14.4 MB)
  hipLaunchKernelGGL(pack_all, dim3(1156), dim3(256), 0, stream, x, w, ws8);
  hipLaunchKernelGGL(conv_main, dim3(64, 4, 1), dim3(512), 0, stream,
                     ws8, bias, (int*)d_out);
}